// Round 2
// baseline (577.720 us; speedup 1.0000x reference)
//
#include <hip/hip_runtime.h>

// MHA forward, MI355X/gfx950 — round 2.
//   K1: QKV = X @ Wqkv^T + b; Q/K -> qkb [8192][2048] bf16 (q pre-scaled 1/8),
//       V -> vtg [64 bh][64 d][2048 t] bf16 (transposed in epilogue).
//   K2: fused attn per (b,h,64 q): swapped-operand scores mfma(K,Q) -> lane-local
//       consecutive-t P; pass1 denominators; pass2 probs float4 stores + packed
//       Ps b64 writes + PV mfma(Vt,P); double-buffered K, raw barriers with
//       separated vmcnt/lgkmcnt waits (prefetch survives barriers).
//   K3: out = attn @ out_w^T + out_b, fp32.

#define DEV __device__ __forceinline__

typedef __attribute__((ext_vector_type(8))) short short8;   // 8 bf16 (MFMA A/B frag)
typedef __attribute__((ext_vector_type(4))) float f32x4;    // MFMA C/D frag

DEV unsigned short f2b(float f) {   // f32 -> bf16 RNE
  union { float f; unsigned u; } v; v.f = f;
  unsigned r = v.u + 0x7fffu + ((v.u >> 16) & 1u);
  return (unsigned short)(r >> 16);
}
DEV unsigned pk2(float lo, float hi) {  // two f32 -> packed bf16x2 (lo = low 16)
  return (unsigned)f2b(lo) | ((unsigned)f2b(hi) << 16);
}
DEV void gl_lds16(const void* g, void* l) {  // async global->LDS, dest = base + lane*16
  __builtin_amdgcn_global_load_lds(
      (const __attribute__((address_space(1))) void*)g,
      (__attribute__((address_space(3))) void*)l, 16, 0, 0);
}
DEV void bar_lgkm() { asm volatile("s_waitcnt lgkmcnt(0)\n\ts_barrier" ::: "memory"); }
DEV void wait_vm0() { asm volatile("s_waitcnt vmcnt(0)" ::: "memory"); }

__global__ void cvt_f32_bf16(const float* __restrict__ src, unsigned short* __restrict__ dst, int n) {
  int i = (blockIdx.x * blockDim.x + threadIdx.x) * 4;
  if (i >= n) return;
  float4 v = *(const float4*)(src + i);
  ushort4 o; o.x = f2b(v.x); o.y = f2b(v.y); o.z = f2b(v.z); o.w = f2b(v.w);
  *(ushort4*)(dst + i) = o;
}

// C = A @ B^T + bias; A[M][K], B[N][K] bf16. 128x128 tile, BK=64, 4 waves (2x2).
// MODE 0: fp32 C (ld=N).  MODE 1: QKV special — n<2048 -> bf16 Cqk (ld 2048,
// q cols scaled 1/8); n>=2048 -> V transposed into Vtg[bh][d][t] (packed 8B).
template<int MODE>
__global__ __launch_bounds__(256, 2) void gemm_bt(
    const unsigned short* __restrict__ A,
    const unsigned short* __restrict__ B,
    const float* __restrict__ bias,
    float* __restrict__ Cf,
    unsigned short* __restrict__ Cqk,
    unsigned short* __restrict__ Vtg,
    int N, int K)
{
  constexpr int BK = 64;
  __shared__ __align__(16) unsigned short As[128*BK];
  __shared__ __align__(16) unsigned short Bs[128*BK];
  const int tid = threadIdx.x, lane = tid & 63, wid = tid >> 6;
  const int lhi = lane >> 4, llo = lane & 15;
  const int m0 = blockIdx.y * 128, n0 = blockIdx.x * 128;
  const int wr = wid >> 1, wc = wid & 1;

  f32x4 acc[4][4] = {};

  const int nsteps = K / BK;
  for (int kt = 0; kt < nsteps; ++kt) {
    __syncthreads();
#pragma unroll
    for (int s = 0; s < 4; ++s) {
      int u = wid*4 + s;
      int a = u*1024 + lane*16;
      int t = a >> 7;
      int cb = (a & 127) ^ ((t & 7) << 4);
      int e = kt*BK + (cb >> 1);
      gl_lds16(A + (size_t)(m0 + t)*K + e, (char*)As + u*1024);
      gl_lds16(B + (size_t)(n0 + t)*K + e, (char*)Bs + u*1024);
    }
    __syncthreads();
#pragma unroll
    for (int kk = 0; kk < 2; ++kk) {
      short8 af[4], bfr[4];
#pragma unroll
      for (int mf = 0; mf < 4; ++mf) {
        int row = wr*64 + mf*16 + llo;
        af[mf] = *(const short8*)((const char*)As + row*128 + ((kk*64 + lhi*16) ^ ((row & 7) << 4)));
      }
#pragma unroll
      for (int nf = 0; nf < 4; ++nf) {
        int row = wc*64 + nf*16 + llo;
        bfr[nf] = *(const short8*)((const char*)Bs + row*128 + ((kk*64 + lhi*16) ^ ((row & 7) << 4)));
      }
#pragma unroll
      for (int mf = 0; mf < 4; ++mf)
#pragma unroll
        for (int nf = 0; nf < 4; ++nf)
          acc[mf][nf] = __builtin_amdgcn_mfma_f32_16x16x32_bf16(af[mf], bfr[nf], acc[mf][nf], 0, 0, 0);
    }
  }
  // epilogue (C/D: row = lhi*4+r, col = llo)
  if (MODE == 0) {
#pragma unroll
    for (int mf = 0; mf < 4; ++mf)
#pragma unroll
      for (int nf = 0; nf < 4; ++nf) {
        int n = n0 + wc*64 + nf*16 + llo;
        float bv = bias[n];
#pragma unroll
        for (int r = 0; r < 4; ++r) {
          int m = m0 + wr*64 + mf*16 + lhi*4 + r;
          Cf[(size_t)m*N + n] = acc[mf][nf][r] + bv;
        }
      }
  } else {
    if (n0 < 2048) {  // Q/K region
#pragma unroll
      for (int mf = 0; mf < 4; ++mf)
#pragma unroll
        for (int nf = 0; nf < 4; ++nf) {
          int n = n0 + wc*64 + nf*16 + llo;
          float bv = bias[n];
          float sc = (n < 1024) ? 0.125f : 1.0f;
#pragma unroll
          for (int r = 0; r < 4; ++r) {
            int m = m0 + wr*64 + mf*16 + lhi*4 + r;
            Cqk[(size_t)m*2048 + n] = f2b((acc[mf][nf][r] + bv) * sc);
          }
        }
    } else {          // V region -> transposed Vtg[bh][d][t], t = token%2048
#pragma unroll
      for (int mf = 0; mf < 4; ++mf)
#pragma unroll
        for (int nf = 0; nf < 4; ++nf) {
          int n = n0 + wc*64 + nf*16 + llo;
          float bv = bias[n];
          int hh = (n - 2048) >> 6, d = (n - 2048) & 63;
          int m = m0 + wr*64 + mf*16 + lhi*4;   // 4-aligned, b fixed across r
          int bb = m >> 11, t = m & 2047;
          ushort4 o;
          o.x = f2b(acc[mf][nf][0] + bv);
          o.y = f2b(acc[mf][nf][1] + bv);
          o.z = f2b(acc[mf][nf][2] + bv);
          o.w = f2b(acc[mf][nf][3] + bv);
          *(ushort4*)(Vtg + ((size_t)((bb << 4) + hh)*64 + d)*2048 + t) = o;
        }
    }
  }
}

// Fused attention. Block = (b,h,qt): 64 q-rows, 4 waves. Wave w owns t-cols
// [w*32,w*32+32) for scores (swapped mfma(K,Q): D[t][q]) and q-rows
// [w*16,w*16+16) for PV (mfma(Vt,P): D[d][q]).
__global__ __launch_bounds__(256, 2) void mha_fused(
    const unsigned short* __restrict__ qk,    // [8192][2048] bf16 (q scaled)
    const unsigned short* __restrict__ vtg,   // [64 bh][64 d][2048 t] bf16
    float* __restrict__ probs,                // [64 bh][2048][2048] f32 (= probs/scale)
    unsigned short* __restrict__ attnb)       // [8192][1024] bf16
{
  constexpr int T = 2048, LD = 2048, QB = 64, TB = 128, NT = T / TB;
  __shared__ __align__(16) unsigned short Qs[QB*64];        //  8 KB, 128B rows swz
  __shared__ __align__(16) unsigned short Kbuf[2][TB*64];   // 32 KB, 128B rows swz
  __shared__ __align__(16) unsigned short Vs[64*TB];        // 16 KB, 256B rows swz
  __shared__ __align__(16) unsigned short Ps[QB*TB];        // 16 KB, 256B rows swz
  __shared__ float lsum[4][QB];
  __shared__ float linv[QB];

  const int tid = threadIdx.x, lane = tid & 63, wid = tid >> 6;
  const int lhi = lane >> 4, llo = lane & 15;
  const int qt = blockIdx.x & 31, bh = blockIdx.x >> 5;
  const int bb = bh >> 4, h = bh & 15;
  const int q0 = qt * QB;
  const size_t tokQ = (size_t)bb*T + q0;

  auto stageK = [&](int tt, unsigned short* buf) {
#pragma unroll
    for (int s = 0; s < 4; ++s) {
      int u = wid*4 + s;
      int a = u*1024 + lane*16;
      int tr = a >> 7;
      int cb = (a & 127) ^ ((tr & 7) << 4);
      gl_lds16(qk + ((size_t)bb*T + tt*TB + tr)*LD + 1024 + h*64 + (cb >> 1),
               (char*)buf + u*1024);
    }
  };
  auto stageV = [&](int tt) {
#pragma unroll
    for (int s = 0; s < 4; ++s) {
      int u = wid*4 + s;
      int a = u*1024 + lane*16;
      int d = a >> 8;
      int cb = (a & 255) ^ ((d & 7) << 4);
      gl_lds16(vtg + ((size_t)bh*64 + d)*T + tt*TB + (cb >> 1),
               (char*)Vs + u*1024);
    }
  };

  // ---- prologue: Q (8 KB) + K0 ----
#pragma unroll
  for (int s = 0; s < 2; ++s) {
    int u = wid*2 + s;
    int a = u*1024 + lane*16;
    int tr = a >> 7;
    int cb = (a & 127) ^ ((tr & 7) << 4);
    gl_lds16(qk + (tokQ + tr)*LD + h*64 + (cb >> 1), (char*)Qs + u*1024);
  }
  stageK(0, Kbuf[0]);
  wait_vm0(); bar_lgkm();

  // Q fragments in registers (loop-invariant): B[q=llo row][d slice]
  short8 qfr[4][2];
#pragma unroll
  for (int qf = 0; qf < 4; ++qf)
#pragma unroll
    for (int kk = 0; kk < 2; ++kk) {
      int row = qf*16 + llo;
      qfr[qf][kk] = *(const short8*)((const char*)Qs + row*128 + ((kk*64 + lhi*16) ^ ((row & 7) << 4)));
    }

  // ---------------- pass 1: denominators ----------------
  float part[4] = {0.f, 0.f, 0.f, 0.f};
  for (int tt = 0; tt < NT; ++tt) {
    if (tt + 1 < NT) stageK(tt + 1, Kbuf[(tt + 1) & 1]);
    f32x4 sacc[2][4] = {};
#pragma unroll
    for (int kk = 0; kk < 2; ++kk) {
      short8 kf[2];
#pragma unroll
      for (int tf = 0; tf < 2; ++tf) {
        int row = wid*32 + tf*16 + llo;
        kf[tf] = *(const short8*)((const char*)Kbuf[tt & 1] + row*128 + ((kk*64 + lhi*16) ^ ((row & 7) << 4)));
      }
#pragma unroll
      for (int tf = 0; tf < 2; ++tf)
#pragma unroll
        for (int qf = 0; qf < 4; ++qf)
          sacc[tf][qf] = __builtin_amdgcn_mfma_f32_16x16x32_bf16(kf[tf], qfr[qf][kk], sacc[tf][qf], 0, 0, 0);
    }
#pragma unroll
    for (int tf = 0; tf < 2; ++tf)
#pragma unroll
      for (int qf = 0; qf < 4; ++qf)
#pragma unroll
        for (int r = 0; r < 4; ++r)
          part[qf] += __expf(sacc[tf][qf][r]);
    wait_vm0(); bar_lgkm();   // K(tt+1) landed everywhere; buffers safe
  }

  // wave-local reduce over lhi, then cross-wave via LDS
#pragma unroll
  for (int qf = 0; qf < 4; ++qf) {
    float v = part[qf];
    v += __shfl_xor(v, 16);
    v += __shfl_xor(v, 32);
    if (lhi == 0) lsum[wid][qf*16 + llo] = v;
  }
  stageK(0, Kbuf[0]);         // restage K0 for pass 2 (overlaps reduction)
  bar_lgkm();
  if (tid < QB) linv[tid] = 1.0f / (lsum[0][tid] + lsum[1][tid] + lsum[2][tid] + lsum[3][tid]);
  wait_vm0(); bar_lgkm();
  float lr[4];
#pragma unroll
  for (int qf = 0; qf < 4; ++qf) lr[qf] = linv[qf*16 + llo];

  // ---------------- pass 2: probs + PV ----------------
  f32x4 pv[4] = {};
  for (int tt = 0; tt < NT; ++tt) {
    stageV(tt);               // Vs free (prev PV done before last barrier)
    f32x4 sacc[2][4] = {};
#pragma unroll
    for (int kk = 0; kk < 2; ++kk) {
      short8 kf[2];
#pragma unroll
      for (int tf = 0; tf < 2; ++tf) {
        int row = wid*32 + tf*16 + llo;
        kf[tf] = *(const short8*)((const char*)Kbuf[tt & 1] + row*128 + ((kk*64 + lhi*16) ^ ((row & 7) << 4)));
      }
#pragma unroll
      for (int tf = 0; tf < 2; ++tf)
#pragma unroll
        for (int qf = 0; qf < 4; ++qf)
          sacc[tf][qf] = __builtin_amdgcn_mfma_f32_16x16x32_bf16(kf[tf], qfr[qf][kk], sacc[tf][qf], 0, 0, 0);
    }
    // exp, normalize, pack to Ps (b64), stash 8p for probs store after barrier
    float4 pst[2][4];
#pragma unroll
    for (int tf = 0; tf < 2; ++tf)
#pragma unroll
      for (int qf = 0; qf < 4; ++qf) {
        float p0 = __expf(sacc[tf][qf][0]) * lr[qf];
        float p1 = __expf(sacc[tf][qf][1]) * lr[qf];
        float p2 = __expf(sacc[tf][qf][2]) * lr[qf];
        float p3 = __expf(sacc[tf][qf][3]) * lr[qf];
        int q = qf*16 + llo;
        int t0 = wid*32 + tf*16 + lhi*4;
        uint2 w2; w2.x = pk2(p0, p1); w2.y = pk2(p2, p3);
        *(uint2*)((char*)Ps + q*256 + ((t0*2) ^ ((q & 7) << 4))) = w2;
        pst[tf][qf] = make_float4(8.f*p0, 8.f*p1, 8.f*p2, 8.f*p3);
      }
    wait_vm0();               // V(tt) landed (issued before scores)
    bar_lgkm();               // publish Vs + Ps; all waves done with Kbuf[tt&1]
    if (tt + 1 < NT) stageK(tt + 1, Kbuf[(tt + 1) & 1]);
    // probs stores (float4, overlap PV)
#pragma unroll
    for (int tf = 0; tf < 2; ++tf)
#pragma unroll
      for (int qf = 0; qf < 4; ++qf) {
        int q = qf*16 + llo;
        int t0 = wid*32 + tf*16 + lhi*4;
        *(float4*)&probs[((size_t)bh*T + q0 + q)*T + tt*TB + t0] = pst[tf][qf];
      }
    // PV: wave w -> q rows [w*16,w*16+16), D[d][q]
#pragma unroll
    for (int kk = 0; kk < 4; ++kk) {
      int rq = wid*16 + llo;
      short8 pb = *(const short8*)((const char*)Ps + rq*256 + ((kk*64 + lhi*16) ^ ((rq & 7) << 4)));
#pragma unroll
      for (int mf = 0; mf < 4; ++mf) {
        int rd = mf*16 + llo;
        short8 va = *(const short8*)((const char*)Vs + rd*256 + ((kk*64 + lhi*16) ^ ((rd & 7) << 4)));
        pv[mf] = __builtin_amdgcn_mfma_f32_16x16x32_bf16(va, pb, pv[mf], 0, 0, 0);
      }
    }
    wait_vm0();               // K(tt+1) + probs stores drained (covered by PV)
    bar_lgkm();
  }

  // attn out: D[d][q] -> lane has 4 consecutive d at q = wid*16+llo
#pragma unroll
  for (int mf = 0; mf < 4; ++mf) {
    int q = wid*16 + llo;
    int d0 = mf*16 + lhi*4;
    ushort4 o;
    o.x = f2b(pv[mf][0]); o.y = f2b(pv[mf][1]);
    o.z = f2b(pv[mf][2]); o.w = f2b(pv[mf][3]);
    *(ushort4*)(attnb + (tokQ + q)*1024 + h*64 + d0) = o;
  }
}

extern "C" void kernel_launch(void* const* d_in, const int* in_sizes, int n_in,
                              void* d_out, int out_size, void* d_ws, size_t ws_size,
                              hipStream_t stream) {
  (void)in_sizes; (void)n_in; (void)out_size; (void)ws_size;
  const float* x    = (const float*)d_in[0];
  const float* wqkv = (const float*)d_in[1];
  const float* bqkv = (const float*)d_in[2];
  const float* wout = (const float*)d_in[3];
  const float* bout = (const float*)d_in[4];

  constexpr int T = 2048, E = 1024;
  constexpr int M = 4 * T;                    // 8192 tokens
  constexpr size_t NX   = (size_t)M * E;      // 8.4M
  constexpr size_t NW1  = (size_t)3 * E * E;
  constexpr size_t NW2  = (size_t)E * E;
  constexpr size_t NQK  = (size_t)M * 2048;   // Q|K packed rows
  constexpr size_t NVT  = (size_t)64 * 64 * T;

  char* ws = (char*)d_ws;                     // ~92 MB total
  unsigned short* xb    = (unsigned short*)ws;  ws += NX  * 2;
  unsigned short* wqkvb = (unsigned short*)ws;  ws += NW1 * 2;
  unsigned short* woutb = (unsigned short*)ws;  ws += NW2 * 2;
  unsigned short* qkb   = (unsigned short*)ws;  ws += NQK * 2;
  unsigned short* vtg   = (unsigned short*)ws;  ws += NVT * 2;
  unsigned short* attnb = (unsigned short*)ws;  ws += NX  * 2;

  cvt_f32_bf16<<<(int)(NX  / 1024), 256, 0, stream>>>(x,    xb,    (int)NX);
  cvt_f32_bf16<<<(int)(NW1 / 1024), 256, 0, stream>>>(wqkv, wqkvb, (int)NW1);
  cvt_f32_bf16<<<(int)(NW2 / 1024), 256, 0, stream>>>(wout, woutb, (int)NW2);

  gemm_bt<1><<<dim3(3*E/128, M/128), 256, 0, stream>>>(
      xb, wqkvb, bqkv, nullptr, qkb, vtg, 3*E, E);

  float* probsOut = (float*)d_out + NX;
  mha_fused<<<4*16*(T/64), 256, 0, stream>>>(qkb, vtg, probsOut, attnb);

  gemm_bt<0><<<dim3(E/128, M/128), 256, 0, stream>>>(
      attnb, woutb, bout, (float*)d_out, nullptr, nullptr, E, E);
}

// Round 3
// 542.872 us; speedup vs baseline: 1.0642x; 1.0642x over previous
//
#include <hip/hip_runtime.h>

// MHA forward, MI355X/gfx950 — round 3.
// Change vs R2: attention pass-2 uses counted vmcnt guards (T4) so probs
// stores are never drained at barriers. Issue order per wave per iter is
// pinned [stageV x4][stageK x4][stores x8] with zero-cost memory fences:
//   B1 guard: vmcnt(12) (V landed; K+stores may fly)
//   B2 guard: vmcnt(8)  (K landed; stores may fly)
// Everything else identical to R2.

#define DEV __device__ __forceinline__

typedef __attribute__((ext_vector_type(8))) short short8;   // 8 bf16 (MFMA A/B frag)
typedef __attribute__((ext_vector_type(4))) float f32x4;    // MFMA C/D frag

DEV unsigned short f2b(float f) {   // f32 -> bf16 RNE
  union { float f; unsigned u; } v; v.f = f;
  unsigned r = v.u + 0x7fffu + ((v.u >> 16) & 1u);
  return (unsigned short)(r >> 16);
}
DEV unsigned pk2(float lo, float hi) {  // two f32 -> packed bf16x2
  return (unsigned)f2b(lo) | ((unsigned)f2b(hi) << 16);
}
DEV void gl_lds16(const void* g, void* l) {  // async global->LDS, dest = base + lane*16
  __builtin_amdgcn_global_load_lds(
      (const __attribute__((address_space(1))) void*)g,
      (__attribute__((address_space(3))) void*)l, 16, 0, 0);
}
DEV void bar_lgkm() { asm volatile("s_waitcnt lgkmcnt(0)\n\ts_barrier" ::: "memory"); }
DEV void wait_vm0() { asm volatile("s_waitcnt vmcnt(0)" ::: "memory"); }

__global__ void cvt_f32_bf16(const float* __restrict__ src, unsigned short* __restrict__ dst, int n) {
  int i = (blockIdx.x * blockDim.x + threadIdx.x) * 4;
  if (i >= n) return;
  float4 v = *(const float4*)(src + i);
  ushort4 o; o.x = f2b(v.x); o.y = f2b(v.y); o.z = f2b(v.z); o.w = f2b(v.w);
  *(ushort4*)(dst + i) = o;
}

// C = A @ B^T + bias; A[M][K], B[N][K] bf16. 128x128 tile, BK=64, 4 waves (2x2).
// MODE 0: fp32 C (ld=N).  MODE 1: QKV special — n<2048 -> bf16 Cqk (ld 2048,
// q cols scaled 1/8); n>=2048 -> V transposed into Vtg[bh][d][t] (packed 8B).
template<int MODE>
__global__ __launch_bounds__(256, 2) void gemm_bt(
    const unsigned short* __restrict__ A,
    const unsigned short* __restrict__ B,
    const float* __restrict__ bias,
    float* __restrict__ Cf,
    unsigned short* __restrict__ Cqk,
    unsigned short* __restrict__ Vtg,
    int N, int K)
{
  constexpr int BK = 64;
  __shared__ __align__(16) unsigned short As[128*BK];
  __shared__ __align__(16) unsigned short Bs[128*BK];
  const int tid = threadIdx.x, lane = tid & 63, wid = tid >> 6;
  const int lhi = lane >> 4, llo = lane & 15;
  const int m0 = blockIdx.y * 128, n0 = blockIdx.x * 128;
  const int wr = wid >> 1, wc = wid & 1;

  f32x4 acc[4][4] = {};

  const int nsteps = K / BK;
  for (int kt = 0; kt < nsteps; ++kt) {
    __syncthreads();
#pragma unroll
    for (int s = 0; s < 4; ++s) {
      int u = wid*4 + s;
      int a = u*1024 + lane*16;
      int t = a >> 7;
      int cb = (a & 127) ^ ((t & 7) << 4);
      int e = kt*BK + (cb >> 1);
      gl_lds16(A + (size_t)(m0 + t)*K + e, (char*)As + u*1024);
      gl_lds16(B + (size_t)(n0 + t)*K + e, (char*)Bs + u*1024);
    }
    __syncthreads();
#pragma unroll
    for (int kk = 0; kk < 2; ++kk) {
      short8 af[4], bfr[4];
#pragma unroll
      for (int mf = 0; mf < 4; ++mf) {
        int row = wr*64 + mf*16 + llo;
        af[mf] = *(const short8*)((const char*)As + row*128 + ((kk*64 + lhi*16) ^ ((row & 7) << 4)));
      }
#pragma unroll
      for (int nf = 0; nf < 4; ++nf) {
        int row = wc*64 + nf*16 + llo;
        bfr[nf] = *(const short8*)((const char*)Bs + row*128 + ((kk*64 + lhi*16) ^ ((row & 7) << 4)));
      }
#pragma unroll
      for (int mf = 0; mf < 4; ++mf)
#pragma unroll
        for (int nf = 0; nf < 4; ++nf)
          acc[mf][nf] = __builtin_amdgcn_mfma_f32_16x16x32_bf16(af[mf], bfr[nf], acc[mf][nf], 0, 0, 0);
    }
  }
  // epilogue (C/D: row = lhi*4+r, col = llo)
  if (MODE == 0) {
#pragma unroll
    for (int mf = 0; mf < 4; ++mf)
#pragma unroll
      for (int nf = 0; nf < 4; ++nf) {
        int n = n0 + wc*64 + nf*16 + llo;
        float bv = bias[n];
#pragma unroll
        for (int r = 0; r < 4; ++r) {
          int m = m0 + wr*64 + mf*16 + lhi*4 + r;
          Cf[(size_t)m*N + n] = acc[mf][nf][r] + bv;
        }
      }
  } else {
    if (n0 < 2048) {  // Q/K region
#pragma unroll
      for (int mf = 0; mf < 4; ++mf)
#pragma unroll
        for (int nf = 0; nf < 4; ++nf) {
          int n = n0 + wc*64 + nf*16 + llo;
          float bv = bias[n];
          float sc = (n < 1024) ? 0.125f : 1.0f;
#pragma unroll
          for (int r = 0; r < 4; ++r) {
            int m = m0 + wr*64 + mf*16 + lhi*4 + r;
            Cqk[(size_t)m*2048 + n] = f2b((acc[mf][nf][r] + bv) * sc);
          }
        }
    } else {          // V region -> transposed Vtg[bh][d][t]
#pragma unroll
      for (int mf = 0; mf < 4; ++mf)
#pragma unroll
        for (int nf = 0; nf < 4; ++nf) {
          int n = n0 + wc*64 + nf*16 + llo;
          float bv = bias[n];
          int hh = (n - 2048) >> 6, d = (n - 2048) & 63;
          int m = m0 + wr*64 + mf*16 + lhi*4;
          int bb = m >> 11, t = m & 2047;
          ushort4 o;
          o.x = f2b(acc[mf][nf][0] + bv);
          o.y = f2b(acc[mf][nf][1] + bv);
          o.z = f2b(acc[mf][nf][2] + bv);
          o.w = f2b(acc[mf][nf][3] + bv);
          *(ushort4*)(Vtg + ((size_t)((bb << 4) + hh)*64 + d)*2048 + t) = o;
        }
    }
  }
}

// Fused attention. Block = (b,h,qt): 64 q-rows, 4 waves. Wave w owns t-cols
// [w*32,w*32+32) for scores (mfma(K,Q): D[t][q]) and q-rows [w*16,w*16+16)
// for PV (mfma(Vt,P): D[d][q]).
__global__ __launch_bounds__(256, 2) void mha_fused(
    const unsigned short* __restrict__ qk,    // [8192][2048] bf16 (q scaled)
    const unsigned short* __restrict__ vtg,   // [64 bh][64 d][2048 t] bf16
    float* __restrict__ probs,                // [64 bh][2048][2048] f32
    unsigned short* __restrict__ attnb)       // [8192][1024] bf16
{
  constexpr int T = 2048, LD = 2048, QB = 64, TB = 128, NT = T / TB;
  __shared__ __align__(16) unsigned short Qs[QB*64];        //  8 KB
  __shared__ __align__(16) unsigned short Kbuf[2][TB*64];   // 32 KB
  __shared__ __align__(16) unsigned short Vs[64*TB];        // 16 KB
  __shared__ __align__(16) unsigned short Ps[QB*TB];        // 16 KB
  __shared__ float lsum[4][QB];
  __shared__ float linv[QB];

  const int tid = threadIdx.x, lane = tid & 63, wid = tid >> 6;
  const int lhi = lane >> 4, llo = lane & 15;
  const int qt = blockIdx.x & 31, bh = blockIdx.x >> 5;
  const int bb = bh >> 4, h = bh & 15;
  const int q0 = qt * QB;
  const size_t tokQ = (size_t)bb*T + q0;

  auto stageK = [&](int tt, unsigned short* buf) {
#pragma unroll
    for (int s = 0; s < 4; ++s) {
      int u = wid*4 + s;
      int a = u*1024 + lane*16;
      int tr = a >> 7;
      int cb = (a & 127) ^ ((tr & 7) << 4);
      gl_lds16(qk + ((size_t)bb*T + tt*TB + tr)*LD + 1024 + h*64 + (cb >> 1),
               (char*)buf + u*1024);
    }
  };
  auto stageV = [&](int tt) {
#pragma unroll
    for (int s = 0; s < 4; ++s) {
      int u = wid*4 + s;
      int a = u*1024 + lane*16;
      int d = a >> 8;
      int cb = (a & 255) ^ ((d & 7) << 4);
      gl_lds16(vtg + ((size_t)bh*64 + d)*T + tt*TB + (cb >> 1),
               (char*)Vs + u*1024);
    }
  };

  // ---- prologue: Q (8 KB) + K0 ----
#pragma unroll
  for (int s = 0; s < 2; ++s) {
    int u = wid*2 + s;
    int a = u*1024 + lane*16;
    int tr = a >> 7;
    int cb = (a & 127) ^ ((tr & 7) << 4);
    gl_lds16(qk + (tokQ + tr)*LD + h*64 + (cb >> 1), (char*)Qs + u*1024);
  }
  stageK(0, Kbuf[0]);
  wait_vm0(); bar_lgkm();

  // Q fragments in registers (loop-invariant)
  short8 qfr[4][2];
#pragma unroll
  for (int qf = 0; qf < 4; ++qf)
#pragma unroll
    for (int kk = 0; kk < 2; ++kk) {
      int row = qf*16 + llo;
      qfr[qf][kk] = *(const short8*)((const char*)Qs + row*128 + ((kk*64 + lhi*16) ^ ((row & 7) << 4)));
    }

  // ---------------- pass 1: denominators ----------------
  float part[4] = {0.f, 0.f, 0.f, 0.f};
  for (int tt = 0; tt < NT; ++tt) {
    if (tt + 1 < NT) stageK(tt + 1, Kbuf[(tt + 1) & 1]);
    f32x4 sacc[2][4] = {};
#pragma unroll
    for (int kk = 0; kk < 2; ++kk) {
      short8 kf[2];
#pragma unroll
      for (int tf = 0; tf < 2; ++tf) {
        int row = wid*32 + tf*16 + llo;
        kf[tf] = *(const short8*)((const char*)Kbuf[tt & 1] + row*128 + ((kk*64 + lhi*16) ^ ((row & 7) << 4)));
      }
#pragma unroll
      for (int tf = 0; tf < 2; ++tf)
#pragma unroll
        for (int qf = 0; qf < 4; ++qf)
          sacc[tf][qf] = __builtin_amdgcn_mfma_f32_16x16x32_bf16(kf[tf], qfr[qf][kk], sacc[tf][qf], 0, 0, 0);
    }
#pragma unroll
    for (int tf = 0; tf < 2; ++tf)
#pragma unroll
      for (int qf = 0; qf < 4; ++qf)
#pragma unroll
        for (int r = 0; r < 4; ++r)
          part[qf] += __expf(sacc[tf][qf][r]);
    wait_vm0(); bar_lgkm();
  }

  // wave-local reduce over lhi groups, then cross-wave via LDS
#pragma unroll
  for (int qf = 0; qf < 4; ++qf) {
    float v = part[qf];
    v += __shfl_xor(v, 16);
    v += __shfl_xor(v, 32);
    if (lhi == 0) lsum[wid][qf*16 + llo] = v;
  }
  stageK(0, Kbuf[0]);                         // K0 for pass 2
  bar_lgkm();                                 // lsum visible
  if (tid < QB) linv[tid] = 1.0f / (lsum[0][tid] + lsum[1][tid] + lsum[2][tid] + lsum[3][tid]);
  stageV(0);                                  // V0
  stageK(1, Kbuf[1]);                         // K1
  asm volatile("s_waitcnt vmcnt(8)" ::: "memory");   // K0 landed (V0+K1 = 8 newer)
  bar_lgkm();                                 // linv visible
  float lr[4];
#pragma unroll
  for (int qf = 0; qf < 4; ++qf) lr[qf] = linv[qf*16 + llo];

  // ---------------- pass 2: probs + PV (counted vmcnt) ----------------
  f32x4 pv[4] = {};
  for (int tt = 0; tt < NT; ++tt) {
    // A: scores from Kbuf[tt&1]
    f32x4 sacc[2][4] = {};
#pragma unroll
    for (int kk = 0; kk < 2; ++kk) {
      short8 kf[2];
#pragma unroll
      for (int tf = 0; tf < 2; ++tf) {
        int row = wid*32 + tf*16 + llo;
        kf[tf] = *(const short8*)((const char*)Kbuf[tt & 1] + row*128 + ((kk*64 + lhi*16) ^ ((row & 7) << 4)));
      }
#pragma unroll
      for (int tf = 0; tf < 2; ++tf)
#pragma unroll
        for (int qf = 0; qf < 4; ++qf)
          sacc[tf][qf] = __builtin_amdgcn_mfma_f32_16x16x32_bf16(kf[tf], qfr[qf][kk], sacc[tf][qf], 0, 0, 0);
    }
    // B: exp, normalize, pack Ps (b64), stash probs values
    float4 pst[2][4];
#pragma unroll
    for (int tf = 0; tf < 2; ++tf)
#pragma unroll
      for (int qf = 0; qf < 4; ++qf) {
        float p0 = __expf(sacc[tf][qf][0]) * lr[qf];
        float p1 = __expf(sacc[tf][qf][1]) * lr[qf];
        float p2 = __expf(sacc[tf][qf][2]) * lr[qf];
        float p3 = __expf(sacc[tf][qf][3]) * lr[qf];
        int q = qf*16 + llo;
        int t0 = wid*32 + tf*16 + lhi*4;
        uint2 w2; w2.x = pk2(p0, p1); w2.y = pk2(p2, p3);
        *(uint2*)((char*)Ps + q*256 + ((t0*2) ^ ((q & 7) << 4))) = w2;
        pst[tf][qf] = make_float4(8.f*p0, 8.f*p1, 8.f*p2, 8.f*p3);
      }
    // B1: guard V(tt) landed; stores/K may remain in flight
    if (tt == 0) asm volatile("s_waitcnt vmcnt(4) lgkmcnt(0)\n\ts_barrier" ::: "memory");
    else         asm volatile("s_waitcnt vmcnt(12) lgkmcnt(0)\n\ts_barrier" ::: "memory");
    // D: PV (reads Ps + Vs)
#pragma unroll
    for (int kk2 = 0; kk2 < 4; ++kk2) {
      int rq = wid*16 + llo;
      short8 pb = *(const short8*)((const char*)Ps + rq*256 + ((kk2*64 + lhi*16) ^ ((rq & 7) << 4)));
#pragma unroll
      for (int mf = 0; mf < 4; ++mf) {
        int rd = mf*16 + llo;
        short8 va = *(const short8*)((const char*)Vs + rd*256 + ((kk2*64 + lhi*16) ^ ((rd & 7) << 4)));
        pv[mf] = __builtin_amdgcn_mfma_f32_16x16x32_bf16(va, pb, pv[mf], 0, 0, 0);
      }
    }
    // B2: guard K(tt+1) landed; stores may remain in flight
    if (tt == 0) asm volatile("s_waitcnt vmcnt(0)\n\ts_barrier" ::: "memory");
    else         asm volatile("s_waitcnt vmcnt(8)\n\ts_barrier" ::: "memory");
    // F: issue next-tile loads FIRST, then stores (order pinned by fences)
    stageV((tt + 1) & 15);                        // dummy wrap at tt=15 (never read)
    asm volatile("" ::: "memory");
    stageK((tt + 2) & 15, Kbuf[tt & 1]);          // dummy wrap at tt>=14 (never read)
    asm volatile("" ::: "memory");
#pragma unroll
    for (int tf = 0; tf < 2; ++tf)
#pragma unroll
      for (int qf = 0; qf < 4; ++qf) {
        int q = qf*16 + llo;
        int t0 = wid*32 + tf*16 + lhi*4;
        *(float4*)&probs[((size_t)bh*T + q0 + q)*T + tt*TB + t0] = pst[tf][qf];
      }
  }

  // attn out: D[d][q], lane has 4 consecutive d at q = wid*16+llo
#pragma unroll
  for (int mf = 0; mf < 4; ++mf) {
    int q = wid*16 + llo;
    int d0 = mf*16 + lhi*4;
    ushort4 o;
    o.x = f2b(pv[mf][0]); o.y = f2b(pv[mf][1]);
    o.z = f2b(pv[mf][2]); o.w = f2b(pv[mf][3]);
    *(ushort4*)(attnb + (tokQ + q)*1024 + h*64 + d0) = o;
  }
}

extern "C" void kernel_launch(void* const* d_in, const int* in_sizes, int n_in,
                              void* d_out, int out_size, void* d_ws, size_t ws_size,
                              hipStream_t stream) {
  (void)in_sizes; (void)n_in; (void)out_size; (void)ws_size;
  const float* x    = (const float*)d_in[0];
  const float* wqkv = (const float*)d_in[1];
  const float* bqkv = (const float*)d_in[2];
  const float* wout = (const float*)d_in[3];
  const float* bout = (const float*)d_in[4];

  constexpr int T = 2048, E = 1024;
  constexpr int M = 4 * T;
  constexpr size_t NX   = (size_t)M * E;
  constexpr size_t NW1  = (size_t)3 * E * E;
  constexpr size_t NW2  = (size_t)E * E;
  constexpr size_t NQK  = (size_t)M * 2048;
  constexpr size_t NVT  = (size_t)64 * 64 * T;

  char* ws = (char*)d_ws;
  unsigned short* xb    = (unsigned short*)ws;  ws += NX  * 2;
  unsigned short* wqkvb = (unsigned short*)ws;  ws += NW1 * 2;
  unsigned short* woutb = (unsigned short*)ws;  ws += NW2 * 2;
  unsigned short* qkb   = (unsigned short*)ws;  ws += NQK * 2;
  unsigned short* vtg   = (unsigned short*)ws;  ws += NVT * 2;
  unsigned short* attnb = (unsigned short*)ws;  ws += NX  * 2;

  cvt_f32_bf16<<<(int)(NX  / 1024), 256, 0, stream>>>(x,    xb,    (int)NX);
  cvt_f32_bf16<<<(int)(NW1 / 1024), 256, 0, stream>>>(wqkv, wqkvb, (int)NW1);
  cvt_f32_bf16<<<(int)(NW2 / 1024), 256, 0, stream>>>(wout, woutb, (int)NW2);

  gemm_bt<1><<<dim3(3*E/128, M/128), 256, 0, stream>>>(
      xb, wqkvb, bqkv, nullptr, qkb, vtg, 3*E, E);

  float* probsOut = (float*)d_out + NX;
  mha_fused<<<4*16*(T/64), 256, 0, stream>>>(qkb, vtg, probsOut, attnb);

  gemm_bt<0><<<dim3(E/128, M/128), 256, 0, stream>>>(
      attnb, woutb, bout, (float*)d_out, nullptr, nullptr, E, E);
}